// Round 4
// baseline (7142.744 us; speedup 1.0000x reference)
//
#include <hip/hip_runtime.h>
#include <stdint.h>

typedef __bf16 bf16;
typedef __bf16 bf16x4 __attribute__((ext_vector_type(4)));
typedef __bf16 bf16x8 __attribute__((ext_vector_type(8)));
typedef float f32x4 __attribute__((ext_vector_type(4)));

#define MFMA16x16x32(A, B, C) __builtin_amdgcn_mfma_f32_16x16x32_bf16((A), (B), (C), 0, 0, 0)

#define B_ 512
#define T_ 100
#define F_ 1024
#define H_ 1024
#define TC_ 25   // T-chunk for XZ staging
#define NBLK_ 512
#define NWAVE_ARRIVALS_ 2048u  // 512 blocks * 4 waves

__device__ __forceinline__ float sigmoid_f(float x) { return 1.0f / (1.0f + __expf(-x)); }
__device__ __forceinline__ float b2bsqrt_f(float x) {
  float s = sqrtf(1.0f + fabsf(x)) - 1.0f;
  return x >= 0.0f ? s : -s;  // x==0 -> s==0, matches sign(0)=0
}

// async global->LDS, 16B/lane; LDS dest = wave-uniform base + lane*16
__device__ __forceinline__ void glds16(const void* g, void* l) {
  __builtin_amdgcn_global_load_lds((const __attribute__((address_space(1))) void*)g,
                                   (__attribute__((address_space(3))) void*)l, 16, 0, 0);
}
// same, but sc0|sc1 (CPol 1|16=17): bypass L2, read at device coherence point (L3)
__device__ __forceinline__ void glds16_dev(const void* g, void* l) {
  __builtin_amdgcn_global_load_lds((const __attribute__((address_space(1))) void*)g,
                                   (__attribute__((address_space(3))) void*)l, 16, 0, 17);
}
// 8B store, write-through to device coherence point (sc0 sc1)
__device__ __forceinline__ void store8_dev(void* p, uint2 v) {
  asm volatile("global_store_dwordx2 %0, %1, off sc0 sc1" : : "v"(p), "v"(v) : "memory");
}

// ---------------- zero-init h slot 0 and barrier counters ----------------
__global__ __launch_bounds__(256) void zero_init(bf16* __restrict__ h0,
                                                 unsigned* __restrict__ bar, int n) {
  int i = blockIdx.x * blockDim.x + threadIdx.x;
  if (i < n) h0[i] = (bf16)0.0f;
  if (i < 128) bar[i] = 0u;
}

// ---------- transpose per gate: fp32 (1024 x 1024) -> bf16 transposed ----------
__global__ __launch_bounds__(256) void tr_kernel(const float* __restrict__ src,
                                                 bf16* __restrict__ dst) {
  __shared__ float tile[32][33];
  int g = blockIdx.z;
  int c0 = blockIdx.x * 32;
  int r0 = blockIdx.y * 32;
  const float* s = src + (size_t)g * 1024 * 1024;
  bf16* d = dst + (size_t)g * 1024 * 1024;
  int tx = threadIdx.x & 31, ty = threadIdx.x >> 5;
  #pragma unroll
  for (int i = 0; i < 32; i += 8)
    tile[ty + i][tx] = s[(size_t)(r0 + ty + i) * 1024 + c0 + tx];
  __syncthreads();
  #pragma unroll
  for (int i = 0; i < 32; i += 8)
    d[(size_t)(c0 + ty + i) * 1024 + r0 + tx] = (bf16)tile[tx][ty + i];
}

// ---------- convert x chunk fp32 -> bf16: xbf[(b*TC+tt), f] = x[b, t0+tt, f] ----------
__global__ __launch_bounds__(256) void convx(const float* __restrict__ x,
                                             bf16* __restrict__ xbf, int t0) {
  int lr = blockIdx.x * 4 + (threadIdx.x >> 6);
  int lane = threadIdx.x & 63;
  unsigned b = (unsigned)lr / 25u;
  unsigned tt = (unsigned)lr - b * 25u;
  const float* src = x + (size_t)(b * 100u + (unsigned)t0 + tt) * 1024;
  bf16* dst = xbf + (size_t)lr * 1024;
  #pragma unroll
  for (int j = 0; j < 4; ++j) {
    f32x4 f = *(const f32x4*)(src + (j * 64 + lane) * 4);
    bf16x4 o;
    o[0] = (bf16)f[0]; o[1] = (bf16)f[1]; o[2] = (bf16)f[2]; o[3] = (bf16)f[3];
    *(bf16x4*)(dst + (j * 64 + lane) * 4) = o;
  }
}

// ---------- prep FC: Bt[c][h] = ln_g[h]*fcw[h,c] (c<10), ones (c==10), 0 else;
//            SA[c] = sum_h Bt[c][h], SA[16+c] = sum_h ln_b[h]*fcw[h,c] + fcb[c] ----------
__global__ __launch_bounds__(256) void prep_fc(const float* __restrict__ lng,
                                               const float* __restrict__ lnb,
                                               const float* __restrict__ fcw,
                                               const float* __restrict__ fcb,
                                               bf16* __restrict__ Bt,
                                               float* __restrict__ SA) {
  __shared__ float red[2][256];
  int c = blockIdx.x;  // 0..15
  int tid = threadIdx.x;
  float pS = 0.f, pA = 0.f;
  #pragma unroll
  for (int j = 0; j < 4; ++j) {
    int h = j * 256 + tid;
    float v;
    if (c < 10) {
      float wv = fcw[h * 10 + c];
      v = lng[h] * wv;
      pS += v;
      pA += lnb[h] * wv;
    } else {
      v = (c == 10) ? 1.0f : 0.0f;
    }
    Bt[c * 1024 + h] = (bf16)v;
  }
  if (c < 10) {
    red[0][tid] = pS; red[1][tid] = pA;
    __syncthreads();
    for (int s = 128; s > 0; s >>= 1) {
      if (tid < s) { red[0][tid] += red[0][tid + s]; red[1][tid] += red[1][tid + s]; }
      __syncthreads();
    }
    if (tid == 0) { SA[c] = red[0][0]; SA[16 + c] = red[1][0] + fcb[c]; }
  }
}

// ---------------- xz chunk GEMM (m97-style): XZc = xbf @ Wt^T ----------------
// xbf (B*TC,1024) bf16 row lr=b*TC+tt; Wt (4096,1024) bf16 row n=g*1024+h.
// out XZc bf16 (TC,4,B,H).
__global__ __launch_bounds__(256) void gemm_xz(const bf16* __restrict__ X,
                                               const bf16* __restrict__ Wt,
                                               bf16* __restrict__ XZc) {
  __shared__ bf16 sA[128 * 32];
  __shared__ bf16 sB[128 * 32];
  const int tid = threadIdx.x;
  const int lane = tid & 63;
  const int w = tid >> 6;
  const int l16 = lane & 15;
  const int quad = lane >> 4;
  const int m0 = blockIdx.y * 128;
  const int n0 = blockIdx.x * 128;
  const int wm = (w >> 1) * 64;
  const int wn = (w & 1) * 64;
  const int rA = lane >> 2;               // 0..15 within an issue
  const int gch = (lane & 3) ^ (rA & 3);  // XOR-swizzled global 16B chunk

  f32x4 acc[4][4] = {};

  for (int kk = 0; kk < 1024; kk += 32) {
    #pragma unroll
    for (int j = 0; j < 2; ++j) {
      int r0 = (w * 2 + j) * 16;
      int r = r0 + rA;
      glds16(X + (size_t)(m0 + r) * 1024 + kk + gch * 8, sA + r0 * 32);
      glds16(Wt + (size_t)(n0 + r) * 1024 + kk + gch * 8, sB + r0 * 32);
    }
    __syncthreads();
    bf16x8 aF[4], bF[4];
    const int slot = quad ^ (l16 & 3);
    #pragma unroll
    for (int mt = 0; mt < 4; ++mt)
      aF[mt] = *(const bf16x8*)(sA + (wm + mt * 16 + l16) * 32 + slot * 8);
    #pragma unroll
    for (int nt = 0; nt < 4; ++nt)
      bF[nt] = *(const bf16x8*)(sB + (wn + nt * 16 + l16) * 32 + slot * 8);
    #pragma unroll
    for (int mt = 0; mt < 4; ++mt)
      #pragma unroll
      for (int nt = 0; nt < 4; ++nt)
        acc[mt][nt] = MFMA16x16x32(aF[mt], bF[nt], acc[mt][nt]);
    __syncthreads();
  }

  #pragma unroll
  for (int mt = 0; mt < 4; ++mt) {
    #pragma unroll
    for (int r = 0; r < 4; ++r) {
      unsigned lr = (unsigned)(m0 + wm + mt * 16 + quad * 4 + r);
      unsigned b = lr / 25u;
      unsigned tt = lr - b * 25u;
      #pragma unroll
      for (int nt = 0; nt < 4; ++nt) {
        int n = n0 + wn + nt * 16 + l16;
        int g = n >> 10;
        int hh = n & 1023;
        XZc[((size_t)(tt * 4 + g) * B_ + b) * H_ + hh] = (bf16)acc[mt][nt][r];
      }
    }
  }
}

// ------------- persistent recurrence: nsteps of Z = xz_t + h_prev @ U + gating -------------
// Cooperative launch, grid (32,16) = 512 blocks x 256 thr (2 blocks/CU co-resident).
// Block tile: 32 b-rows x (32 h x 4 gates). wave w = gate w. c-state in registers.
// Cross-XCD h exchange: sc0sc1 write-through stores + sc0sc1 L2-bypass staging reads;
// per-step grid barrier = per-wave RELEASE fetch_add + thread-0 spin (no L2 invalidate).
__global__ __launch_bounds__(256, 2) void lstm_persist(
    int t0, int nsteps, int first,
    const bf16* __restrict__ XZc,    // (TC,4,B,H) chunk
    const bf16* __restrict__ Ut,     // (4096,1024): row n=g*1024+h, col k
    const float* __restrict__ bias,  // (4,H)
    bf16* __restrict__ hseq,         // (T+1,B,H) global base
    float* __restrict__ cst,         // (B,H) carry between chunk launches
    unsigned* __restrict__ bar) {    // (T) per-step arrival counters
  __shared__ bf16 sA[32 * 64];
  __shared__ bf16 sB[128 * 64];      // row R = g*32 + rr
  __shared__ float sZ[32 * 132];     // 32 b-rows x 128 cols (g*32+h'), +4 pad

  const int tid = threadIdx.x;
  const int lane = tid & 63;
  const int w = tid >> 6;  // gate id
  const int l16 = lane & 15;
  const int quad = lane >> 4;
  const int hn0 = blockIdx.x * 32;
  const int bm0 = blockIdx.y * 32;
  const int rL = lane >> 3;
  const int gch = (lane & 7) ^ rL;

  // gating thread map: (b-row rr, 4 consecutive h)
  const int rr = tid >> 3;
  const int cc = (tid & 7) * 4;
  const int b = bm0 + rr;
  const int h = hn0 + cc;

  f32x4 bs[4];
  #pragma unroll
  for (int g = 0; g < 4; ++g) bs[g] = *(const f32x4*)(bias + g * 1024 + h);

  f32x4 co;
  if (first) { co[0] = 0.f; co[1] = 0.f; co[2] = 0.f; co[3] = 0.f; }
  else co = *(const f32x4*)(cst + (size_t)b * 1024 + h);

  for (int s = 0; s < nsteps; ++s) {
    const int t = t0 + s;
    const bf16* hprev = hseq + (size_t)t * (B_ * H_);
    f32x4 acc[2][2] = {};

    for (int kk = 0; kk < 1024; kk += 64) {
      // sA: 32 rows of hprev, 8 per wave (L2-bypass: data came from other XCDs)
      glds16_dev(hprev + (size_t)(bm0 + w * 8 + rL) * 1024 + kk + gch * 8,
                 sA + (w * 8) * 64);
      // sB: 128 Ut rows (4 gates x 32), 32 per wave (normal cached: L2-hot)
      #pragma unroll
      for (int j = 0; j < 4; ++j) {
        int r0 = w * 32 + j * 8;
        int R = r0 + rL;
        int g2 = R >> 5, rr2 = R & 31;
        glds16(Ut + (size_t)((g2 << 10) + hn0 + rr2) * 1024 + kk + gch * 8,
               sB + r0 * 64);
      }
      __syncthreads();
      #pragma unroll
      for (int kh = 0; kh < 2; ++kh) {
        const int slot = (kh * 4 + quad) ^ (l16 & 7);
        bf16x8 aF[2], bF[2];
        #pragma unroll
        for (int mt = 0; mt < 2; ++mt)
          aF[mt] = *(const bf16x8*)(sA + (mt * 16 + l16) * 64 + slot * 8);
        #pragma unroll
        for (int nt = 0; nt < 2; ++nt)
          bF[nt] = *(const bf16x8*)(sB + (w * 32 + nt * 16 + l16) * 64 + slot * 8);
        #pragma unroll
        for (int mt = 0; mt < 2; ++mt)
          #pragma unroll
          for (int nt = 0; nt < 2; ++nt)
            acc[mt][nt] = MFMA16x16x32(aF[mt], bF[nt], acc[mt][nt]);
      }
      __syncthreads();
    }

    // dump Z (C/D layout: row=quad*4+r, col=l16) into shared for cross-gate gather
    #pragma unroll
    for (int mt = 0; mt < 2; ++mt)
      #pragma unroll
      for (int nt = 0; nt < 2; ++nt)
        #pragma unroll
        for (int r = 0; r < 4; ++r)
          sZ[(mt * 16 + quad * 4 + r) * 132 + w * 32 + nt * 16 + l16] = acc[mt][nt][r];
    __syncthreads();

    f32x4 z[4]; bf16x4 xz[4];
    #pragma unroll
    for (int g = 0; g < 4; ++g) {
      z[g] = *(const f32x4*)(sZ + rr * 132 + g * 32 + cc);
      xz[g] = *(const bf16x4*)(XZc + ((size_t)(s * 4 + g) * B_ + b) * H_ + h);
    }

    bf16x4 hb;
    #pragma unroll
    for (int jj = 0; jj < 4; ++jj) {
      float I  = sigmoid_f(z[0][jj] + (float)xz[0][jj] + bs[0][jj]);
      float Fg = sigmoid_f(z[1][jj] + (float)xz[1][jj] + bs[1][jj]);
      float O  = sigmoid_f(z[2][jj] + (float)xz[2][jj] + bs[2][jj]);
      float Ct = b2bsqrt_f(z[3][jj] + (float)xz[3][jj] + bs[3][jj]);
      float c2 = Fg * co[jj] + I * Ct;
      co[jj] = c2;
      hb[jj] = (bf16)(O * b2bsqrt_f(c2));
    }
    {
      bf16* hp = hseq + (size_t)(t + 1) * (B_ * H_) + (size_t)b * 1024 + h;
      uint2 d; __builtin_memcpy(&d, &hb, 8);
      store8_dev(hp, d);
    }

    if (s != nsteps - 1) {
      __syncthreads();  // all waves' stores issued+drained (vmcnt0 before barrier)
      if (lane == 0)
        __hip_atomic_fetch_add(&bar[t], 1u, __ATOMIC_RELEASE, __HIP_MEMORY_SCOPE_AGENT);
      if (tid == 0) {
        unsigned v;
        do {
          __builtin_amdgcn_s_sleep(1);
          v = __hip_atomic_load(&bar[t], __ATOMIC_RELAXED, __HIP_MEMORY_SCOPE_AGENT);
        } while (v < NWAVE_ARRIVALS_);
      }
      __syncthreads();
    }
  }
  *(f32x4*)(cst + (size_t)b * 1024 + h) = co;
}

// ------------- LN+FC as MFMA GEMM: (51200 x 1024) @ (1024 x 16) -------------
__global__ __launch_bounds__(256) void ln_fc_kernel(
    const bf16* __restrict__ hseq1, const bf16* __restrict__ Bt,
    const float* __restrict__ SA, float* __restrict__ out) {
  __shared__ bf16 sA[64 * 64];
  __shared__ bf16 sBt[16 * 1040];
  __shared__ float sLg[4][16 * 17];
  __shared__ float sSq[4][16];
  const int tid = threadIdx.x;
  const int lane = tid & 63;
  const int w = tid >> 6;
  const int l16 = lane & 15;
  const int quad = lane >> 4;
  const int m0 = blockIdx.x * 64;
  const int rL = lane >> 3;
  const int gch = (lane & 7) ^ rL;

  #pragma unroll
  for (int i = 0; i < 8; ++i) {
    int ch = tid + i * 256;
    int n = ch >> 7, k8 = ch & 127;
    *(bf16x8*)(sBt + n * 1040 + k8 * 8) = *(const bf16x8*)(Bt + n * 1024 + k8 * 8);
  }

  f32x4 acc = {};
  float sq = 0.f;

  for (int kk = 0; kk < 1024; kk += 64) {
    #pragma unroll
    for (int j = 0; j < 2; ++j) {
      int r0 = (w * 2 + j) * 8;
      int r = r0 + rL;
      glds16(hseq1 + (size_t)(m0 + r) * 1024 + kk + gch * 8, sA + r0 * 64);
    }
    __syncthreads();
    #pragma unroll
    for (int kh = 0; kh < 2; ++kh) {
      const int slot = (kh * 4 + quad) ^ (l16 & 7);
      bf16x8 aF = *(const bf16x8*)(sA + (w * 16 + l16) * 64 + slot * 8);
      bf16x8 bF = *(const bf16x8*)(sBt + l16 * 1040 + kk + kh * 32 + quad * 8);
      acc = MFMA16x16x32(aF, bF, acc);
      #pragma unroll
      for (int e = 0; e < 8; ++e) { float f = (float)aF[e]; sq += f * f; }
    }
    __syncthreads();
  }

  sq += __shfl_xor(sq, 16, 64);
  sq += __shfl_xor(sq, 32, 64);

  #pragma unroll
  for (int r = 0; r < 4; ++r)
    sLg[w][(quad * 4 + r) * 17 + l16] = acc[r];
  if (quad == 0) sSq[w][l16] = sq;
  __syncthreads();

  if (lane < 16) {
    int row = lane;
    float sum = sLg[w][row * 17 + 10];
    float ssq = sSq[w][row];
    float mu = sum * (1.0f / 1024.0f);
    float var = ssq * (1.0f / 1024.0f) - mu * mu;
    float rs = rsqrtf(var + 1e-5f);
    int rg = m0 + w * 16 + row;
    int t = rg >> 9, b = rg & 511;
    float* op = out + ((size_t)b * 100 + t) * 10;
    #pragma unroll
    for (int c = 0; c < 10; ++c)
      op[c] = rs * (sLg[w][row * 17 + c] - mu * SA[c]) + SA[16 + c];
  }
}

extern "C" void kernel_launch(void* const* d_in, const int* in_sizes, int n_in,
                              void* d_out, int out_size, void* d_ws, size_t ws_size,
                              hipStream_t stream) {
  (void)in_sizes; (void)n_in; (void)out_size; (void)ws_size;
  const float* x    = (const float*)d_in[0];  // (B,T,F)
  const float* W    = (const float*)d_in[1];  // (4,F,H)
  const float* U    = (const float*)d_in[2];  // (4,H,H)
  const float* bias = (const float*)d_in[3];  // (4,H)
  const float* lng  = (const float*)d_in[4];
  const float* lnb  = (const float*)d_in[5];
  const float* fcw  = (const float*)d_in[6];  // (H,10)
  const float* fcb  = (const float*)d_in[7];
  float* out = (float*)d_out;

  char* ws = (char*)d_ws;
  size_t off = 0;
  bf16* Wt    = (bf16*)(ws + off); off += (size_t)4 * F_ * H_ * 2;          //   8.4 MB
  bf16* Ut    = (bf16*)(ws + off); off += (size_t)4 * H_ * H_ * 2;          //   8.4 MB
  bf16* XZc   = (bf16*)(ws + off); off += (size_t)TC_ * 4 * B_ * H_ * 2;    // 104.9 MB
  bf16* hseq  = (bf16*)(ws + off); off += (size_t)(T_ + 1) * B_ * H_ * 2;   // 105.9 MB
  float* cst  = (float*)(ws + off); off += (size_t)B_ * H_ * 4;             //   2.1 MB
  bf16* xbf   = (bf16*)(ws + off); off += (size_t)B_ * TC_ * F_ * 2;        //  26.2 MB
  bf16* Bt    = (bf16*)(ws + off); off += (size_t)16 * H_ * 2;              //  32 KB
  float* SA   = (float*)(ws + off); off += 128;
  unsigned* bar = (unsigned*)(ws + off); off += 512;
  // total ~256 MB

  zero_init<<<(B_ * H_ + 255) / 256, 256, 0, stream>>>(hseq, bar, B_ * H_);
  tr_kernel<<<dim3(32, 32, 4), 256, 0, stream>>>(W, Wt);
  tr_kernel<<<dim3(32, 32, 4), 256, 0, stream>>>(U, Ut);
  prep_fc<<<16, 256, 0, stream>>>(lng, lnb, fcw, fcb, Bt, SA);

  for (int chunk = 0; chunk < T_ / TC_; ++chunk) {
    int t0 = chunk * TC_;
    convx<<<(B_ * TC_) / 4, 256, 0, stream>>>(x, xbf, t0);
    gemm_xz<<<dim3(32, (B_ * TC_) / 128), 256, 0, stream>>>(xbf, Wt, XZc);

    int nsteps = TC_;
    int first = (chunk == 0) ? 1 : 0;
    const bf16* xzp = XZc;
    const bf16* utp = Ut;
    const float* bp = bias;
    bf16* hp = hseq;
    float* cp = cst;
    unsigned* brp = bar;
    void* args[] = {&t0, &nsteps, &first, &xzp, &utp, &bp, &hp, &cp, &brp};
    hipLaunchCooperativeKernel((const void*)lstm_persist, dim3(32, 16), dim3(256),
                               args, 0, stream);
  }

  ln_fc_kernel<<<(B_ * T_) / 64, 256, 0, stream>>>(hseq + (size_t)B_ * H_, Bt, SA, out);
}